// Round 1
// baseline (102.457 us; speedup 1.0000x reference)
//
#include <hip/hip_runtime.h>

// Problem: N=16384 rows, D=256, fp32.
// out = (sum(W) - N) / N^2  where W = P_hat P_hat^T  (rows normalized to unit L2).
// Identity: sum(W) = || sum_i p_hat_i ||^2  -> single streaming pass, no Gram matrix.

#define NROWS 16384
#define DIM   256
#define NBLK  64      // partial-sum blocks
#define TPB   256     // 4 waves/block

__global__ __launch_bounds__(TPB) void cosreg_partial(const float* __restrict__ pts,
                                                      double* __restrict__ partial) {
    const int lane = threadIdx.x & 63;
    const int wid  = threadIdx.x >> 6;            // wave in block: 0..3
    const int gw   = blockIdx.x * 4 + wid;        // global wave id: 0..255
    const int totalWaves = NBLK * 4;              // 256

    // lane l owns components 4l .. 4l+3 of the running sum vector
    double a0 = 0.0, a1 = 0.0, a2 = 0.0, a3 = 0.0;

    for (int r = gw; r < NROWS; r += totalWaves) {
        const float4 v = reinterpret_cast<const float4*>(pts + (size_t)r * DIM)[lane];
        // per-lane partial sum of squares (fp64)
        double sq = (double)v.x * (double)v.x
                  + (double)v.y * (double)v.y
                  + (double)v.z * (double)v.z
                  + (double)v.w * (double)v.w;
        // wave-wide reduce across 64 lanes
        #pragma unroll
        for (int m = 1; m < 64; m <<= 1) sq += __shfl_xor(sq, m, 64);
        const double inv = 1.0 / sqrt(sq);
        a0 += (double)v.x * inv;
        a1 += (double)v.y * inv;
        a2 += (double)v.z * inv;
        a3 += (double)v.w * inv;
    }

    // block-level reduce: 4 waves -> one 256-double vector in LDS
    __shared__ double sblk[DIM];
    sblk[threadIdx.x] = 0.0;
    __syncthreads();
    #pragma unroll
    for (int w = 0; w < 4; ++w) {
        if (wid == w) {
            sblk[lane * 4 + 0] += a0;
            sblk[lane * 4 + 1] += a1;
            sblk[lane * 4 + 2] += a2;
            sblk[lane * 4 + 3] += a3;
        }
        __syncthreads();
    }
    partial[(size_t)blockIdx.x * DIM + threadIdx.x] = sblk[threadIdx.x];
}

__global__ __launch_bounds__(TPB) void cosreg_final(const double* __restrict__ partial,
                                                    float* __restrict__ out) {
    // s[d] = sum over blocks of partial[b*DIM + d]   (coalesced per iteration)
    double s = 0.0;
    #pragma unroll 4
    for (int b = 0; b < NBLK; ++b) s += partial[(size_t)b * DIM + threadIdx.x];

    double sq = s * s;
    #pragma unroll
    for (int m = 1; m < 64; m <<= 1) sq += __shfl_xor(sq, m, 64);

    __shared__ double red[TPB / 64];
    const int lane = threadIdx.x & 63;
    const int wid  = threadIdx.x >> 6;
    if (lane == 0) red[wid] = sq;
    __syncthreads();
    if (threadIdx.x == 0) {
        double tot = 0.0;
        #pragma unroll
        for (int w = 0; w < TPB / 64; ++w) tot += red[w];
        const double n = (double)NROWS;
        out[0] = (float)((tot - n) / (n * n));
    }
}

extern "C" void kernel_launch(void* const* d_in, const int* in_sizes, int n_in,
                              void* d_out, int out_size, void* d_ws, size_t ws_size,
                              hipStream_t stream) {
    const float* pts = (const float*)d_in[0];
    float* out = (float*)d_out;
    double* partial = (double*)d_ws;   // needs NBLK*DIM*8 = 128 KiB

    cosreg_partial<<<NBLK, TPB, 0, stream>>>(pts, partial);
    cosreg_final<<<1, TPB, 0, stream>>>(partial, out);
}

// Round 2
// 70.939 us; speedup vs baseline: 1.4443x; 1.4443x over previous
//
#include <hip/hip_runtime.h>
#include <math.h>

// out = (sum(W) - N) / N^2,  W = P_hat P_hat^T (rows L2-normalized)
// Identity: sum(W) = || sum_i p_hat_i ||^2  -> one streaming pass over the input.
//
// Stage 1: NB blocks x 256 threads (NB=2048 -> 32 waves/CU, full occupancy).
//          One wave handles rows r = gw, gw+4*NB, ... (2 rows at NB=2048).
//          Row-norm reduce + rsqrt in fp32 (error budget in sum(W) is ~18 abs;
//          fp32 contributes ~1e-2). s-vector accumulation in fp64.
//          Block reduce 4 waves -> 256 doubles -> partial[blk][d] (coalesced).
// Stage 2: 64 blocks sum NB/64 partial rows each -> out2[64][256] (coalesced).
// Stage 3: 1 block sums 64 rows -> s[d], then ||s||^2 and the scalar epilogue.

#define NROWS 16384
#define DIM   256
#define TPB   256

__global__ __launch_bounds__(TPB) void cosreg_s1(const float* __restrict__ pts,
                                                 double* __restrict__ partial,
                                                 int nblk) {
    const int lane = threadIdx.x & 63;
    const int wid  = threadIdx.x >> 6;
    const int gw   = blockIdx.x * 4 + wid;
    const int nw   = nblk * 4;

    double a0 = 0.0, a1 = 0.0, a2 = 0.0, a3 = 0.0;

    for (int r = gw; r < NROWS; r += nw) {
        const float4 v = reinterpret_cast<const float4*>(pts + (size_t)r * DIM)[lane];
        float sq = v.x * v.x + v.y * v.y + v.z * v.z + v.w * v.w;
        #pragma unroll
        for (int m = 1; m < 64; m <<= 1) sq += __shfl_xor(sq, m, 64);
        const float inv = 1.0f / sqrtf(sq);
        a0 += (double)(v.x * inv);
        a1 += (double)(v.y * inv);
        a2 += (double)(v.z * inv);
        a3 += (double)(v.w * inv);
    }

    __shared__ double sblk[DIM];
    sblk[threadIdx.x] = 0.0;
    __syncthreads();
    #pragma unroll
    for (int w = 0; w < 4; ++w) {
        if (wid == w) {
            sblk[lane * 4 + 0] += a0;
            sblk[lane * 4 + 1] += a1;
            sblk[lane * 4 + 2] += a2;
            sblk[lane * 4 + 3] += a3;
        }
        __syncthreads();
    }
    partial[(size_t)blockIdx.x * DIM + threadIdx.x] = sblk[threadIdx.x];
}

__global__ __launch_bounds__(TPB) void cosreg_s2(const double* __restrict__ partial,
                                                 double* __restrict__ out2,
                                                 int groups) {  // groups = nblk/64
    const double* base = partial + (size_t)blockIdx.x * groups * DIM;
    double s = 0.0;
    #pragma unroll 8
    for (int k = 0; k < groups; ++k) s += base[(size_t)k * DIM + threadIdx.x];
    out2[(size_t)blockIdx.x * DIM + threadIdx.x] = s;
}

__global__ __launch_bounds__(TPB) void cosreg_s3(const double* __restrict__ out2,
                                                 float* __restrict__ out) {
    double s = 0.0;
    #pragma unroll 8
    for (int j = 0; j < 64; ++j) s += out2[(size_t)j * DIM + threadIdx.x];

    double sq = s * s;
    #pragma unroll
    for (int m = 1; m < 64; m <<= 1) sq += __shfl_xor(sq, m, 64);

    __shared__ double red[TPB / 64];
    const int lane = threadIdx.x & 63;
    const int wid  = threadIdx.x >> 6;
    if (lane == 0) red[wid] = sq;
    __syncthreads();
    if (threadIdx.x == 0) {
        double tot = 0.0;
        #pragma unroll
        for (int w = 0; w < TPB / 64; ++w) tot += red[w];
        const double n = (double)NROWS;
        out[0] = (float)((tot - n) / (n * n));
    }
}

extern "C" void kernel_launch(void* const* d_in, const int* in_sizes, int n_in,
                              void* d_out, int out_size, void* d_ws, size_t ws_size,
                              hipStream_t stream) {
    const float* pts = (const float*)d_in[0];
    float* out = (float*)d_out;

    // Size stage-1 grid by available workspace: nblk*256 + 64*256 doubles.
    int nblk = 2048;
    size_t need = ((size_t)nblk + 64) * DIM * sizeof(double);
    if (ws_size < need) {
        long cap = (long)(ws_size / (DIM * sizeof(double))) - 64;
        nblk = (int)(cap & ~63L);
        if (nblk < 64) nblk = 64;  // 128 KiB floor (worked in round 1)
    }

    double* partial = (double*)d_ws;
    double* out2    = partial + (size_t)nblk * DIM;

    cosreg_s1<<<nblk, TPB, 0, stream>>>(pts, partial, nblk);
    cosreg_s2<<<64,   TPB, 0, stream>>>(partial, out2, nblk / 64);
    cosreg_s3<<<1,    TPB, 0, stream>>>(out2, out);
}